// Round 2
// baseline (123.364 us; speedup 1.0000x reference)
//
#include <hip/hip_runtime.h>

#define H 1536
#define HK 8
#define HV 16
#define DK 64
#define DV 64
#define KEY_DIM 512
#define VALUE_DIM 1024
#define CONV_DIM 2048
#define NROWS1 3104
#define NBLK 256
#define DEC0 240      // decode blocks 240..255 (lightest phase-1 load: single W_out row)

// Monotonic barrier state in module .bss (zero at load, never reset — safe across
// warmups, graph replay, rocprof counter-replay). Counters (RMW) and flags (poll)
// live on separate 128B lines so spin reads never queue against arrivals.
struct BarrierState {
    alignas(128) unsigned cnt1;   // 256 arrivals per launch
    alignas(128) unsigned flag1;  // completed phase-1 episodes
    alignas(128) unsigned cnt2;   // 16 arrivals per launch
    alignas(128) unsigned flag2;  // completed phase-2 episodes
};
__device__ BarrierState g_bar;

__device__ __forceinline__ float wave_reduce_sum(float v) {
#pragma unroll
    for (int off = 32; off > 0; off >>= 1) v += __shfl_xor(v, off, 64);
    return v;
}
__device__ __forceinline__ float dot4(float4 a, float4 b) {
    return a.x * b.x + a.y * b.y + a.z * b.z + a.w * b.w;
}

__global__ __launch_bounds__(256, 1) void fused_decode(
        const float* __restrict__ x,
        const float* __restrict__ Wqkv, const float* __restrict__ Wz,
        const float* __restrict__ Wa,   const float* __restrict__ Wb,
        const float* __restrict__ Wout,
        const float* __restrict__ conv_w, const float* __restrict__ conv_cache,
        const float* __restrict__ A_log, const float* __restrict__ dt_bias,
        const float* __restrict__ norm_w,
        const float* __restrict__ state,
        float* __restrict__ ws,                 // [3072]: qkv | z
        float* __restrict__ og,                 // [1024]
        float* __restrict__ y) {                // [1536]
    const int tid  = threadIdx.x;
    const int lane = tid & 63;
    const int wv   = tid >> 6;
    const int blk  = blockIdx.x;
    const int wg   = blk * 4 + wv;              // 0..1023
    const int hblk = blk - DEC0;                // >=0: this block owns head hblk
    const bool isdec = (hblk >= 0);

    __shared__ float s_state[DK * DV];          // 16 KB
    __shared__ float q_s[64], k_s[64], v_s[64];
    __shared__ float red_r[256], red_o[256];
    __shared__ float scal[3];                   // decay, beta, k·q
    __shared__ float s_ab[2];                   // a-dot, b-dot for this head

    // ============ issue ALL loads up front (maximize loads in flight) ============
    const float4* x4 = (const float4*)x;
    const int r0 = wg * 3;                      // 3 rows/wave covers 0..3071 exactly
    const float4* wA = (const float4*)((r0   < CONV_DIM) ? Wqkv + (size_t)r0*H       : Wz + (size_t)(r0-CONV_DIM)*H);
    const float4* wB = (const float4*)((r0+1 < CONV_DIM) ? Wqkv + (size_t)(r0+1)*H   : Wz + (size_t)(r0+1-CONV_DIM)*H);
    const float4* wC = (const float4*)((r0+2 < CONV_DIM) ? Wqkv + (size_t)(r0+2)*H   : Wz + (size_t)(r0+2-CONV_DIM)*H);

    float4 rx[6], rA[6], rB[6], rC[6];
#pragma unroll
    for (int j = 0; j < 6; ++j) rx[j] = x4[lane + 64*j];
#pragma unroll
    for (int j = 0; j < 6; ++j) rA[j] = wA[lane + 64*j];
#pragma unroll
    for (int j = 0; j < 6; ++j) rB[j] = wB[lane + 64*j];
#pragma unroll
    for (int j = 0; j < 6; ++j) rC[j] = wC[lane + 64*j];

    // W_out prefetch (consumed in phase 3). Blocks 0..127 carry a second row.
    float4 wo0[4], wo1[4];
    {
        const float4* w4 = (const float4*)(Wout + (size_t)wg * VALUE_DIM);
#pragma unroll
        for (int j = 0; j < 4; ++j) wo0[j] = w4[lane + 64*j];
    }
    if (wg < 512) {
        const float4* w4 = (const float4*)(Wout + (size_t)(1024 + wg) * VALUE_DIM);
#pragma unroll
        for (int j = 0; j < 4; ++j) wo1[j] = w4[lane + 64*j];
    }

    // Decode-block extras, all ws-independent, overlapped with phase 1:
    //  - own W_a / W_b row (waves 0/1)
    //  - conv cache-tap partial sums + tap-3 weight (waves 0..2)
    //  - A_log/dt_bias scalars (wave 3 lane 0)
    //  - state -> LDS
    float4 rAB[6];
    const bool abwave = isdec && (wv < 2);
    if (abwave) {
        const float4* w4 = (const float4*)(((wv == 0) ? Wa : Wb) + (size_t)hblk * H);
#pragma unroll
        for (int j = 0; j < 6; ++j) rAB[j] = w4[lane + 64*j];
    }
    float pre = 0.f, w3 = 0.f;
    int qkvrow = 0;
    if (isdec && wv < 3) {
        if (wv == 0)      qkvrow = (hblk >> 1) * 64 + lane;              // q (kv-group)
        else if (wv == 1) qkvrow = KEY_DIM + (hblk >> 1) * 64 + lane;    // k
        else              qkvrow = 2 * KEY_DIM + hblk * 64 + lane;       // v
        pre = conv_cache[qkvrow*3+0] * conv_w[qkvrow*4+0]
            + conv_cache[qkvrow*3+1] * conv_w[qkvrow*4+1]
            + conv_cache[qkvrow*3+2] * conv_w[qkvrow*4+2];
        w3  = conv_w[qkvrow*4+3];
    }
    float r_alog = 0.f, r_dtb = 0.f;
    if (isdec && wv == 3 && lane == 0) { r_alog = A_log[hblk]; r_dtb = dt_bias[hblk]; }
    if (isdec) {
        const float4* st4 = (const float4*)(state + (size_t)hblk * DK * DV);
        float4* ss4 = (float4*)s_state;
#pragma unroll
        for (int j = 0; j < 4; ++j) ss4[tid + 256*j] = st4[tid + 256*j];
    }

    // ============ phase 1 compute ============
    float a0 = 0.f, a1 = 0.f, a2 = 0.f;
#pragma unroll
    for (int j = 0; j < 6; ++j) {
        a0 += dot4(rA[j], rx[j]);
        a1 += dot4(rB[j], rx[j]);
        a2 += dot4(rC[j], rx[j]);
    }
    a0 = wave_reduce_sum(a0);
    a1 = wave_reduce_sum(a1);
    a2 = wave_reduce_sum(a2);
    if (lane == 0) { ws[r0] = a0; ws[r0+1] = a1; ws[r0+2] = a2; }
    if (abwave) {
        float ab = 0.f;
#pragma unroll
        for (int j = 0; j < 6; ++j) ab += dot4(rAB[j], rx[j]);
        ab = wave_reduce_sum(ab);
        if (lane == 0) s_ab[wv] = ab;
    }

    __syncthreads();                       // drain ws / s_ab stores (vmcnt0 before barrier)
    unsigned ep = 0;
    if (tid == 0) {
        unsigned t = __hip_atomic_fetch_add(&g_bar.cnt1, 1u, __ATOMIC_ACQ_REL,
                                            __HIP_MEMORY_SCOPE_AGENT);
        ep = t >> 8;                       // episode == launch index since module load
        if ((t & 255u) == 255u)
            __hip_atomic_store(&g_bar.flag1, ep + 1u, __ATOMIC_RELEASE,
                               __HIP_MEMORY_SCOPE_AGENT);
    }

    // ============ phase 2: decode, blocks 240..255 only ============
    if (isdec) {
        if (tid == 0) {                    // only 16 pollers on flag1
            while (__hip_atomic_load(&g_bar.flag1, __ATOMIC_ACQUIRE,
                                     __HIP_MEMORY_SCOPE_AGENT) <= ep)
                __builtin_amdgcn_s_sleep(8);
        }
        __syncthreads();

        if (wv < 3) {
            float raw = pre + ws[qkvrow] * w3;          // single coalesced ws load
            float c = raw / (1.f + expf(-raw));         // silu
            if (wv == 2) v_s[lane] = c;
            else {
                float ssum = wave_reduce_sum(c * c);
                float inv = rsqrtf(ssum + 1e-12f);      // l2_normalize
                if (wv == 0) q_s[lane] = c * inv * 0.125f;   // * Dk^-0.5
                else         k_s[lane] = c * inv;
            }
        } else if (lane == 0) {
            float aa = s_ab[0] + r_dtb;
            float sp = (aa > 20.f) ? aa : log1pf(expf(aa));  // softplus
            scal[0] = expf(-expf(r_alog) * sp);              // decay
            scal[1] = 1.f / (1.f + expf(-s_ab[1]));          // beta
        }
        __syncthreads();

        float pr = 0.f, po = 0.f;
        const int k0 = wv * 16;
#pragma unroll
        for (int kk = 0; kk < 16; ++kk) {
            float s = s_state[(k0 + kk) * 64 + lane];   // 2-way LDS alias: free
            pr += s * k_s[k0 + kk];
            po += s * q_s[k0 + kk];
        }
        red_r[tid] = pr;
        red_o[tid] = po;
        if (wv == 0) {
            float t = wave_reduce_sum(k_s[lane] * q_s[lane]);
            if (lane == 0) scal[2] = t;
        }
        __syncthreads();

        if (tid < 64) {
            const float decay = scal[0], beta = scal[1], kq = scal[2];
            float r = (red_r[tid] + red_r[64+tid] + red_r[128+tid] + red_r[192+tid]) * decay;
            float o = (red_o[tid] + red_o[64+tid] + red_o[128+tid] + red_o[192+tid]) * decay;
            float delta = (v_s[tid] - r) * beta;
            float outv  = o + delta * kq;               // new_state^T q, unmaterialized
            float ssum = wave_reduce_sum(outv * outv);
            float inv = rsqrtf(ssum * (1.f / 64.f) + 1e-6f);
            float zz  = ws[CONV_DIM + hblk * 64 + tid];
            float gate = zz / (1.f + expf(-zz));        // silu(z)
            og[hblk * 64 + tid] = norm_w[tid] * outv * inv * gate;
        }
        __syncthreads();                   // drain og stores
        if (tid == 0) {
            unsigned t2 = __hip_atomic_fetch_add(&g_bar.cnt2, 1u, __ATOMIC_ACQ_REL,
                                                 __HIP_MEMORY_SCOPE_AGENT);
            if ((t2 & 15u) == 15u)
                __hip_atomic_store(&g_bar.flag2, (t2 >> 4) + 1u, __ATOMIC_RELEASE,
                                   __HIP_MEMORY_SCOPE_AGENT);
        }
    }

    // ============ wait for og, then phase 3 from preloaded registers ============
    if (tid == 0) {
        while (__hip_atomic_load(&g_bar.flag2, __ATOMIC_ACQUIRE,
                                 __HIP_MEMORY_SCOPE_AGENT) <= ep)
            __builtin_amdgcn_s_sleep(16);
    }
    __syncthreads();

    const float4* og4 = (const float4*)og;
    const float4 g0 = og4[lane];
    const float4 g1 = og4[lane + 64];
    const float4 g2 = og4[lane + 128];
    const float4 g3 = og4[lane + 192];
    float acc = dot4(wo0[0], g0) + dot4(wo0[1], g1) + dot4(wo0[2], g2) + dot4(wo0[3], g3);
    acc = wave_reduce_sum(acc);
    if (lane == 0) y[wg] = acc;
    if (wg < 512) {
        float acc2 = dot4(wo1[0], g0) + dot4(wo1[1], g1) + dot4(wo1[2], g2) + dot4(wo1[3], g3);
        acc2 = wave_reduce_sum(acc2);
        if (lane == 0) y[1024 + wg] = acc2;
    }
}

extern "C" void kernel_launch(void* const* d_in, const int* in_sizes, int n_in,
                              void* d_out, int out_size, void* d_ws, size_t ws_size,
                              hipStream_t stream) {
    const float* x     = (const float*)d_in[0];
    const float* Wqkv  = (const float*)d_in[1];
    const float* Wz    = (const float*)d_in[2];
    const float* Wa    = (const float*)d_in[3];
    const float* Wb    = (const float*)d_in[4];
    const float* Wout  = (const float*)d_in[5];
    const float* convw = (const float*)d_in[6];
    const float* Alog  = (const float*)d_in[7];
    const float* dtb   = (const float*)d_in[8];
    const float* normw = (const float*)d_in[9];
    const float* state = (const float*)d_in[10];
    const float* cch   = (const float*)d_in[11];

    float* ws = (float*)d_ws;              // [0,3072): qkv|z
    float* og = ws + NROWS1;               // 16B-aligned (3104*4 % 16 == 0)
    float* y  = (float*)d_out;

    fused_decode<<<NBLK, 256, 0, stream>>>(x, Wqkv, Wz, Wa, Wb, Wout, convw, cch,
                                           Alog, dtb, normw, state, ws, og, y);
}

// Round 3
// 111.107 us; speedup vs baseline: 1.1103x; 1.1103x over previous
//
#include <hip/hip_runtime.h>

#define H 1536
#define HK 8
#define HV 16
#define DK 64
#define DV 64
#define KEY_DIM 512
#define VALUE_DIM 1024
#define CONV_DIM 2048
#define NROWS1 (CONV_DIM + VALUE_DIM + HV + HV)   // 3104

// Decode-head completion counter. Reset by K1 block 0 each launch: same-stream
// kernel ordering guarantees the previous launch's K2 has fully drained before
// K1 runs, and K1 fully drains before K2 starts, so the reset can never race
// with pollers. Lives in module .bss, never touched by workspace poisoning.
__device__ unsigned g_done;

__device__ __forceinline__ float wave_reduce_sum(float v) {
#pragma unroll
    for (int off = 32; off > 0; off >>= 1) v += __shfl_xor(v, off, 64);
    return v;
}
__device__ __forceinline__ float dot4(float4 a, float4 b) {
    return a.x * b.x + a.y * b.y + a.z * b.z + a.w * b.w;
}

// K1: fused GEMV for W_qkv (2048), W_z (1024), W_a (16), W_b (16) vs x[1536].
// One 64-lane wave per row; 6 float4 loads per lane. (Proven round-0 kernel.)
__global__ __launch_bounds__(256) void gemv_in(
        const float* __restrict__ x,
        const float* __restrict__ Wqkv, const float* __restrict__ Wz,
        const float* __restrict__ Wa,   const float* __restrict__ Wb,
        float* __restrict__ ws) {
    if (blockIdx.x == 0 && threadIdx.x == 0)
        __hip_atomic_store(&g_done, 0u, __ATOMIC_RELAXED, __HIP_MEMORY_SCOPE_AGENT);
    const int wave = threadIdx.x >> 6;
    const int lane = threadIdx.x & 63;
    const int row  = blockIdx.x * 4 + wave;          // 776 blocks * 4 = 3104
    const float* wrow;
    if (row < CONV_DIM)                       wrow = Wqkv + (size_t)row * H;
    else if (row < CONV_DIM + VALUE_DIM)      wrow = Wz + (size_t)(row - CONV_DIM) * H;
    else if (row < CONV_DIM + VALUE_DIM + HV) wrow = Wa + (size_t)(row - CONV_DIM - VALUE_DIM) * H;
    else                                      wrow = Wb + (size_t)(row - CONV_DIM - VALUE_DIM - HV) * H;
    const float4* w4 = (const float4*)wrow;
    const float4* x4 = (const float4*)x;
    float acc = 0.f;
#pragma unroll
    for (int j = 0; j < 6; ++j) {                    // 1536/4/64 = 6
        float4 a = w4[lane + 64 * j];
        float4 b = x4[lane + 64 * j];
        acc += a.x * b.x + a.y * b.y + a.z * b.z + a.w * b.w;
    }
    acc = wave_reduce_sum(acc);
    if (lane == 0) ws[row] = acc;
}

// K2: decode (blocks 0..15, one head each, round-0 proven math) + output GEMV
// (all 384 blocks, 1 row/wave) joined by a 16-arrival counter. Deadlock-free:
// capacity >= 5 blocks/CU so all 384 blocks are co-resident regardless of
// dispatch order, and decode blocks never wait before bumping g_done.
__global__ __launch_bounds__(256) void decode_out(
        const float* __restrict__ ws,                 // [qkv 2048 | z 1024 | a 16 | b 16]
        const float* __restrict__ conv_w,             // [2048,4]
        const float* __restrict__ conv_cache,         // [2048,3]
        const float* __restrict__ A_log, const float* __restrict__ dt_bias,
        const float* __restrict__ norm_w,             // [64]
        const float* __restrict__ state,              // [16,64,64]
        const float* __restrict__ Wout,               // [1536,1024]
        float* __restrict__ og,                       // [1024]
        float* __restrict__ y) {                      // [1536]
    const int tid  = threadIdx.x;
    const int lane = tid & 63;
    const int wv   = tid >> 6;
    const int blk  = blockIdx.x;
    const int row  = blk * 4 + wv;                    // 0..1535
    const bool isdec = (blk < HV);

    __shared__ float q_s[64], k_s[64], v_s[64];
    __shared__ float red_r[256], red_o[256];
    __shared__ float scal[3];                         // decay, beta, k·q

    // Consumers: stream W_out row into registers NOW, overlapping decode.
    // The asm pin forces the loads to be issued+consumed here (the compiler
    // sank these past the spin in rounds 1-2: VGPR_Count 72/96 evidence).
    float4 wo[4];
    if (!isdec) {
        const float4* w4 = (const float4*)(Wout + (size_t)row * VALUE_DIM);
#pragma unroll
        for (int j = 0; j < 4; ++j) wo[j] = w4[lane + 64 * j];
        asm volatile("" :: "v"(wo[0].x), "v"(wo[1].x), "v"(wo[2].x), "v"(wo[3].x));
    }

    if (isdec) {
        const int h = blk;
        // Phase A: conv + activation for the q/k/v rows this head needs.
        if (wv < 3) {
            int i;
            if (wv == 0)      i = (h >> 1) * 64 + lane;                // q row (kv-group repeat)
            else if (wv == 1) i = KEY_DIM + (h >> 1) * 64 + lane;      // k row
            else              i = 2 * KEY_DIM + h * 64 + lane;         // v row
            float raw = conv_cache[i * 3 + 0] * conv_w[i * 4 + 0]
                      + conv_cache[i * 3 + 1] * conv_w[i * 4 + 1]
                      + conv_cache[i * 3 + 2] * conv_w[i * 4 + 2]
                      + ws[i]                 * conv_w[i * 4 + 3];
            float c = raw / (1.f + expf(-raw));           // silu
            if (wv == 2) {
                v_s[lane] = c;
            } else {
                float ss  = wave_reduce_sum(c * c);
                float inv = rsqrtf(ss + 1e-12f);          // l2_normalize
                if (wv == 0) q_s[lane] = c * inv * 0.125f;  // * Dk^-0.5
                else         k_s[lane] = c * inv;
            }
        } else if (lane == 0) {
            float aa = ws[CONV_DIM + VALUE_DIM + h] + dt_bias[h];
            float sp = (aa > 20.f) ? aa : log1pf(expf(aa));  // softplus
            scal[0] = expf(-expf(A_log[h]) * sp);            // decay = exp(g)
            float braw = ws[CONV_DIM + VALUE_DIM + HV + h];
            scal[1] = 1.f / (1.f + expf(-braw));             // beta
        }
        __syncthreads();

        // Phase B: partial dots over the K dimension (each quarter covers 16 k's).
        const float* st = state + (size_t)h * DK * DV;
        float pr = 0.f, po = 0.f;
        const int k0 = wv * 16;
#pragma unroll
        for (int kk = 0; kk < 16; ++kk) {
            float s = st[(k0 + kk) * 64 + lane];          // coalesced over v
            pr += s * k_s[k0 + kk];
            po += s * q_s[k0 + kk];
        }
        red_r[tid] = pr;
        red_o[tid] = po;
        if (wv == 0) {                                    // k·q scalar
            float t = wave_reduce_sum(k_s[lane] * q_s[lane]);
            if (lane == 0) scal[2] = t;
        }
        __syncthreads();

        // Phase C: combine, delta rule, gated RMSNorm.
        if (tid < 64) {
            const float decay = scal[0], beta = scal[1], kq = scal[2];
            float r = (red_r[tid] + red_r[64 + tid] + red_r[128 + tid] + red_r[192 + tid]) * decay;
            float o = (red_o[tid] + red_o[64 + tid] + red_o[128 + tid] + red_o[192 + tid]) * decay;
            float delta = (v_s[tid] - r) * beta;
            float outv  = o + delta * kq;                 // new_state^T q, unmaterialized
            float ss  = wave_reduce_sum(outv * outv);
            float inv = rsqrtf(ss * (1.f / 64.f) + 1e-6f);
            float zz  = ws[CONV_DIM + h * 64 + tid];
            float gate = zz / (1.f + expf(-zz));          // silu(z)
            og[h * 64 + tid] = norm_w[tid] * outv * inv * gate;
        }
        __syncthreads();                                  // og stores issued by all lanes' view
        if (tid == 0)                                     // RELEASE flushes og to coherence point
            __hip_atomic_fetch_add(&g_done, 1u, __ATOMIC_RELEASE,
                                   __HIP_MEMORY_SCOPE_AGENT);
    }

    // 16-arrival join: one poller per block on the RMW line (reads served at the
    // coherence point — the mechanism that was promptly visible in round 1).
    if (tid == 0) {
        while (__hip_atomic_load(&g_done, __ATOMIC_ACQUIRE,
                                 __HIP_MEMORY_SCOPE_AGENT) < (unsigned)HV)
            __builtin_amdgcn_s_sleep(2);
    }
    __syncthreads();

    // Decode blocks load their W_out rows late (they were busy decoding).
    if (isdec) {
        const float4* w4 = (const float4*)(Wout + (size_t)row * VALUE_DIM);
#pragma unroll
        for (int j = 0; j < 4; ++j) wo[j] = w4[lane + 64 * j];
    }

    // Output GEMV: y[row] = W_out[row] . og   (same summation order as round 0)
    const float4* og4 = (const float4*)og;
    float acc = 0.f;
    {
        float4 b0 = og4[lane];
        float4 b1 = og4[lane + 64];
        float4 b2 = og4[lane + 128];
        float4 b3 = og4[lane + 192];
        acc += dot4(wo[0], b0);
        acc += dot4(wo[1], b1);
        acc += dot4(wo[2], b2);
        acc += dot4(wo[3], b3);
    }
    acc = wave_reduce_sum(acc);
    if (lane == 0) y[row] = acc;
}

extern "C" void kernel_launch(void* const* d_in, const int* in_sizes, int n_in,
                              void* d_out, int out_size, void* d_ws, size_t ws_size,
                              hipStream_t stream) {
    const float* x     = (const float*)d_in[0];
    const float* Wqkv  = (const float*)d_in[1];
    const float* Wz    = (const float*)d_in[2];
    const float* Wa    = (const float*)d_in[3];
    const float* Wb    = (const float*)d_in[4];
    const float* Wout  = (const float*)d_in[5];
    const float* convw = (const float*)d_in[6];
    const float* Alog  = (const float*)d_in[7];
    const float* dtb   = (const float*)d_in[8];
    const float* normw = (const float*)d_in[9];
    const float* state = (const float*)d_in[10];
    const float* cch   = (const float*)d_in[11];

    float* ws = (float*)d_ws;              // [0,3104): qkv|z|a|b
    float* og = ws + NROWS1;               // [3104,4128): 16B-aligned (3104*4 % 16 == 0)
    float* y  = (float*)d_out;

    gemv_in<<<NROWS1 / 4, 256, 0, stream>>>(x, Wqkv, Wz, Wa, Wb, ws);
    decode_out<<<H / 4, 256, 0, stream>>>(ws, convw, cch, Alog, dtb, normw, state,
                                          Wout, og, y);
}

// Round 4
// 101.607 us; speedup vs baseline: 1.2141x; 1.0935x over previous
//
#include <hip/hip_runtime.h>

#define H 1536
#define HK 8
#define HV 16
#define DK 64
#define DV 64
#define KEY_DIM 512
#define VALUE_DIM 1024
#define CONV_DIM 2048
#define NROWS1 (CONV_DIM + VALUE_DIM + HV + HV)   // 3104

__device__ __forceinline__ float wave_reduce_sum(float v) {
#pragma unroll
    for (int off = 32; off > 0; off >>= 1) v += __shfl_xor(v, off, 64);
    return v;
}
__device__ __forceinline__ float dot4(float4 a, float4 b) {
    return a.x * b.x + a.y * b.y + a.z * b.z + a.w * b.w;
}
__device__ __forceinline__ float conv_silu(int i,
        const float* __restrict__ ws, const float* __restrict__ conv_w,
        const float* __restrict__ conv_cache) {
    float raw = conv_cache[i * 3 + 0] * conv_w[i * 4 + 0]
              + conv_cache[i * 3 + 1] * conv_w[i * 4 + 1]
              + conv_cache[i * 3 + 2] * conv_w[i * 4 + 2]
              + ws[i]                 * conv_w[i * 4 + 3];
    return raw / (1.f + expf(-raw));               // silu
}

// K1: fused GEMV for W_qkv (2048), W_z (1024), W_a (16), W_b (16) vs x[1536].
// One 64-lane wave per row; 6 float4 loads per lane. (Round-0 proven kernel.)
__global__ __launch_bounds__(256) void gemv_in(
        const float* __restrict__ x,
        const float* __restrict__ Wqkv, const float* __restrict__ Wz,
        const float* __restrict__ Wa,   const float* __restrict__ Wb,
        float* __restrict__ ws) {
    const int wave = threadIdx.x >> 6;
    const int lane = threadIdx.x & 63;
    const int row  = blockIdx.x * 4 + wave;          // 776 blocks * 4 = 3104
    const float* wrow;
    if (row < CONV_DIM)                       wrow = Wqkv + (size_t)row * H;
    else if (row < CONV_DIM + VALUE_DIM)      wrow = Wz + (size_t)(row - CONV_DIM) * H;
    else if (row < CONV_DIM + VALUE_DIM + HV) wrow = Wa + (size_t)(row - CONV_DIM - VALUE_DIM) * H;
    else                                      wrow = Wb + (size_t)(row - CONV_DIM - VALUE_DIM - HV) * H;
    const float4* w4 = (const float4*)wrow;
    const float4* x4 = (const float4*)x;
    float acc = 0.f;
#pragma unroll
    for (int j = 0; j < 6; ++j) {                    // 1536/4/64 = 6
        float4 a = w4[lane + 64 * j];
        float4 b = x4[lane + 64 * j];
        acc += a.x * b.x + a.y * b.y + a.z * b.z + a.w * b.w;
    }
    acc = wave_reduce_sum(acc);
    if (lane == 0) ws[row] = acc;
}

// K2: each block REDUNDANTLY recomputes the full 16-head decode into LDS (no
// cross-block dependency whatsoever), then computes its own 16 rows of
// y = W_out @ og. 96 blocks x 512 threads; wave w <-> head-pair w (shared q/k
// computed once per pair). State re-reads (96 x 256 KB) are L2-resident.
// Per-head math replicates the round-0 decode_core expressions and reduction
// order exactly (quarter accumulators combined left-to-right, same shuffle
// trees), so og and y match the proven kernel bitwise.
__global__ __launch_bounds__(512) void decode_y(
        const float* __restrict__ ws,                 // [qkv 2048 | z 1024 | a 16 | b 16]
        const float* __restrict__ conv_w,             // [2048,4]
        const float* __restrict__ conv_cache,         // [2048,3]
        const float* __restrict__ A_log, const float* __restrict__ dt_bias,
        const float* __restrict__ norm_w,             // [64]
        const float* __restrict__ state,              // [16,64,64]
        const float* __restrict__ Wout,               // [1536,1024]
        float* __restrict__ y) {                      // [1536]
    const int tid  = threadIdx.x;
    const int lane = tid & 63;
    const int wv   = tid >> 6;                        // 0..7 == head pair

    __shared__ float og_s[VALUE_DIM];                 // 4 KB

    // ---- shared q/k for this pair (kv-group repeat: heads 2*wv, 2*wv+1) ----
    const int iq = wv * 64 + lane;                    // q row
    const int ik = KEY_DIM + wv * 64 + lane;          // k row
    float cq = conv_silu(iq, ws, conv_w, conv_cache);
    float ck = conv_silu(ik, ws, conv_w, conv_cache);
    float qn = cq * rsqrtf(wave_reduce_sum(cq * cq) + 1e-12f) * 0.125f;  // * Dk^-0.5
    float kn = ck * rsqrtf(wave_reduce_sum(ck * ck) + 1e-12f);
    float kq = wave_reduce_sum(kn * qn);              // k·q scalar

#pragma unroll
    for (int hh = 0; hh < 2; ++hh) {
        const int h = 2 * wv + hh;
        // v row + per-head scalars (computed redundantly by all lanes: same
        // scalar math on broadcast values -> deterministic).
        float cv = conv_silu(2 * KEY_DIM + h * 64 + lane, ws, conv_w, conv_cache);
        float aa = ws[CONV_DIM + VALUE_DIM + h] + dt_bias[h];
        float sp = (aa > 20.f) ? aa : log1pf(expf(aa));     // softplus
        float decay = expf(-expf(A_log[h]) * sp);
        float braw = ws[CONV_DIM + VALUE_DIM + HV + h];
        float beta = 1.f / (1.f + expf(-braw));

        // state contraction: 4 quarter accumulators, left-to-right combine
        // (replicates decode_core's red_r[tid]+red_r[64+tid]+... order).
        const float* st = state + (size_t)h * DK * DV;
        float pr[4] = {0.f, 0.f, 0.f, 0.f};
        float po[4] = {0.f, 0.f, 0.f, 0.f};
#pragma unroll
        for (int qq = 0; qq < 4; ++qq) {
#pragma unroll
            for (int kk = 0; kk < 16; ++kk) {
                const int kidx = qq * 16 + kk;
                float s  = st[kidx * 64 + lane];      // coalesced over v
                pr[qq] += s * __shfl(kn, kidx, 64);
                po[qq] += s * __shfl(qn, kidx, 64);
            }
        }
        float r = (((pr[0] + pr[1]) + pr[2]) + pr[3]) * decay;
        float o = (((po[0] + po[1]) + po[2]) + po[3]) * decay;
        float delta = (cv - r) * beta;
        float outv  = o + delta * kq;                 // new_state^T q, unmaterialized
        float ssum = wave_reduce_sum(outv * outv);
        float inv = rsqrtf(ssum * (1.f / 64.f) + 1e-6f);
        float zz  = ws[CONV_DIM + h * 64 + lane];
        float gate = zz / (1.f + expf(-zz));          // silu(z)
        og_s[h * 64 + lane] = norm_w[lane] * outv * inv * gate;
    }
    __syncthreads();

    // ---- y rows: 16 per block, 2 per wave; og from LDS (bitwise == global og)
    const float4* og4 = (const float4*)og_s;
    const float4 b0 = og4[lane];
    const float4 b1 = og4[lane + 64];
    const float4 b2 = og4[lane + 128];
    const float4 b3 = og4[lane + 192];
#pragma unroll
    for (int j = 0; j < 2; ++j) {
        const int row = blockIdx.x * 16 + wv * 2 + j;
        const float4* w4 = (const float4*)(Wout + (size_t)row * VALUE_DIM);
        float acc = 0.f;
        acc += dot4(w4[lane],       b0);
        acc += dot4(w4[lane + 64],  b1);
        acc += dot4(w4[lane + 128], b2);
        acc += dot4(w4[lane + 192], b3);
        acc = wave_reduce_sum(acc);
        if (lane == 0) y[row] = acc;
    }
}

extern "C" void kernel_launch(void* const* d_in, const int* in_sizes, int n_in,
                              void* d_out, int out_size, void* d_ws, size_t ws_size,
                              hipStream_t stream) {
    const float* x     = (const float*)d_in[0];
    const float* Wqkv  = (const float*)d_in[1];
    const float* Wz    = (const float*)d_in[2];
    const float* Wa    = (const float*)d_in[3];
    const float* Wb    = (const float*)d_in[4];
    const float* Wout  = (const float*)d_in[5];
    const float* convw = (const float*)d_in[6];
    const float* Alog  = (const float*)d_in[7];
    const float* dtb   = (const float*)d_in[8];
    const float* normw = (const float*)d_in[9];
    const float* state = (const float*)d_in[10];
    const float* cch   = (const float*)d_in[11];

    float* ws = (float*)d_ws;              // [0,3104): qkv|z|a|b
    float* y  = (float*)d_out;

    gemv_in<<<NROWS1 / 4, 256, 0, stream>>>(x, Wqkv, Wz, Wa, Wb, ws);
    decode_y<<<H / 16, 512, 0, stream>>>(ws, convw, cch, Alog, dtb, normw, state,
                                         Wout, y);
}